// Round 5
// baseline (627.067 us; speedup 1.0000x reference)
//
#include <hip/hip_runtime.h>
#include <hip/hip_bf16.h>
#include <stdint.h>

// ---------------------------------------------------------------------------
// SCARF embedding: X=[anchor;positive] (16384x512) -> 6x (GEMM+bias+ReLU)
// fp32-accurate via bf16x3 split MFMA (AhBh + AhBl + AlBh).
// GEMM: 256x256 tile, BK=32, 8 waves, read-ahead pipelined inner loop,
// ONE barrier per K-tile, late vmcnt drain, setprio, XOR-swizzled
// hi/lo-interleaved operand layout (pre-swizzled global producers ->
// linear global_load_lds -> XOR ds_read; bank-conflict-free, verified 0).
// ---------------------------------------------------------------------------

typedef __bf16 bf16x8 __attribute__((ext_vector_type(8)));
typedef float  f32x4  __attribute__((ext_vector_type(4)));
typedef unsigned short u16x8 __attribute__((ext_vector_type(8)));

__device__ __forceinline__ void gload_lds16(const void* g, void* l) {
  __builtin_amdgcn_global_load_lds(
      (const __attribute__((address_space(1))) uint32_t*)g,
      (__attribute__((address_space(3))) uint32_t*)l, 16, 0, 0);
}

__device__ __forceinline__ void fsplit(float v, uint16_t& ho, uint16_t& lo) {
  __bf16 hb = (__bf16)v;                 // RNE
  float  r  = v - (float)hb;
  __bf16 lb = (__bf16)r;
  ho = __builtin_bit_cast(uint16_t, hb);
  lo = __builtin_bit_cast(uint16_t, lb);
}

// --- mask dtype detection: 1 = byte-bool, 0 = int32 ------------------------
__global__ void detect_mask_kernel(const uint8_t* __restrict__ mask,
                                   int* __restrict__ flag) {
  if (threadIdx.x == 0 && blockIdx.x == 0) {
    uint32_t or_hi = 0;
    for (int i = 0; i < 256; ++i)
      or_hi |= ((const uint32_t*)mask)[i] & 0xFFFFFF00u;
    *flag = (or_hi != 0) ? 1 : 0;
  }
}

// --- corruption + split + op-layout pack -----------------------------------
__global__ void pack_kernel(const float* __restrict__ anchor,
                            const float* __restrict__ rnd,
                            const uint8_t* __restrict__ mask,
                            const int* __restrict__ mask_is_bytes,
                            uint16_t* __restrict__ Xop) {
  int t = blockIdx.x * 256 + threadIdx.x;    // 524288 threads
  int row = t >> 6;
  int idx = t & 63;
  int g = idx >> 2, c = idx & 3;
  int kbase = idx * 8;
  const float4* ap = (const float4*)(anchor + (size_t)row * 512 + kbase);
  const float4* rp = (const float4*)(rnd + (size_t)row * 512 + kbase);
  float a[8], r[8];
  *(float4*)&a[0] = ap[0]; *(float4*)&a[4] = ap[1];
  *(float4*)&r[0] = rp[0]; *(float4*)&r[4] = rp[1];
  uint32_t mb;
  if (*mask_is_bytes) {
    const uint32_t* mp = (const uint32_t*)(mask + (size_t)row * 512 + kbase);
    uint32_t w0 = mp[0], w1 = mp[1];
    mb = 0;
#pragma unroll
    for (int j = 0; j < 4; ++j) {
      mb |= ((w0 >> (8 * j)) & 1u) << j;
      mb |= ((w1 >> (8 * j)) & 1u) << (4 + j);
    }
  } else {
    const int* mi = (const int*)mask + (size_t)row * 512 + kbase;
    int4 m0 = ((const int4*)mi)[0], m1 = ((const int4*)mi)[1];
    mb = (m0.x ? 1u : 0) | (m0.y ? 2u : 0) | (m0.z ? 4u : 0) | (m0.w ? 8u : 0) |
         (m1.x ? 16u : 0) | (m1.y ? 32u : 0) | (m1.z ? 64u : 0) | (m1.w ? 128u : 0);
  }
  u16x8 ah, al, ph, pl;
#pragma unroll
  for (int j = 0; j < 8; ++j) {
    uint16_t h, lo;
    fsplit(a[j], h, lo); ah[j] = h; al[j] = lo;
    float pv = ((mb >> j) & 1u) ? r[j] : a[j];
    fsplit(pv, h, lo); ph[j] = h; pl[j] = lo;
  }
  int s = row & 7;                         // (row+8192)&7 == row&7
  size_t base = ((size_t)row * 16 + g) * 64;
  *(u16x8*)(Xop + base + (size_t)((c ^ s)) * 8) = ah;
  *(u16x8*)(Xop + base + (size_t)(((c + 4) ^ s)) * 8) = al;
  size_t pbase = ((size_t)(row + 8192) * 16 + g) * 64;
  *(u16x8*)(Xop + pbase + (size_t)((c ^ s)) * 8) = ph;
  *(u16x8*)(Xop + pbase + (size_t)(((c + 4) ^ s)) * 8) = pl;
}

// --- weight prep: W (Kx1024 f32) -> op-layout NxK hi/lo --------------------
__global__ void wprep_kernel(const float* __restrict__ W,
                             uint16_t* __restrict__ Bop, int K) {
  __shared__ float tbuf[32][33];
  int g = blockIdx.x, n0 = blockIdx.y * 32;
  int tid = threadIdx.x;
#pragma unroll
  for (int i = 0; i < 4; ++i)
    tbuf[(tid >> 5) + i * 8][tid & 31] =
        W[((size_t)g * 32 + (tid >> 5) + i * 8) * 1024 + n0 + (tid & 31)];
  __syncthreads();
  if (tid < 128) {
    int nl = tid >> 2, c = tid & 3;
    int n = n0 + nl, s = n & 7;
    u16x8 hi, lo;
#pragma unroll
    for (int j = 0; j < 8; ++j) {
      uint16_t h, l2;
      fsplit(tbuf[c * 8 + j][nl], h, l2);
      hi[j] = h; lo[j] = l2;
    }
    size_t base = ((size_t)n * (K / 32) + g) * 64;
    *(u16x8*)(Bop + base + (size_t)((c ^ s)) * 8) = hi;
    *(u16x8*)(Bop + base + (size_t)(((c + 4) ^ s)) * 8) = lo;
  }
}

// --- pipelined split-bf16 GEMM: C = relu(A @ W^T + bias) -------------------
__device__ __forceinline__ void mfma_row(f32x4* accrow, bf16x8 aH, bf16x8 aL,
                                         const bf16x8* bh, const bf16x8* bl) {
#pragma unroll
  for (int n = 0; n < 4; ++n) {
    accrow[n] = __builtin_amdgcn_mfma_f32_16x16x32_bf16(aH, bh[n], accrow[n], 0, 0, 0);
    accrow[n] = __builtin_amdgcn_mfma_f32_16x16x32_bf16(aH, bl[n], accrow[n], 0, 0, 0);
    accrow[n] = __builtin_amdgcn_mfma_f32_16x16x32_bf16(aL, bh[n], accrow[n], 0, 0, 0);
  }
}

template <int K, bool LAST>
__global__ __launch_bounds__(512, 2) void gemm_kernel(
    const uint16_t* __restrict__ Aop, const uint16_t* __restrict__ Bop,
    const float* __restrict__ bias,
    uint16_t* __restrict__ Yop, float* __restrict__ Yf) {
  constexpr int KG = K / 32;
  __shared__ uint16_t sA[2][256 * 64];
  __shared__ uint16_t sB[2][256 * 64];

  // XCD-chunked swizzle: 256 blocks, xcd = bid&7 owns 8 M-tiles x 4 N-tiles
  int bid = blockIdx.x;
  int xcd = bid & 7, lid = bid >> 3;
  int tm = xcd * 8 + (lid >> 2), tn = lid & 3;
  const int brow = tm * 256, bcol = tn * 256;

  const int tid = threadIdx.x;
  const int l = tid & 63, w = tid >> 6;
  const int wr = w >> 2, wc = w & 3;       // 2x4 wave grid; per-wave C 128x64
  const int l15 = l & 15, c16 = l >> 4;    // frag col/row + k-chunk

  f32x4 acc[8][4];
#pragma unroll
  for (int m = 0; m < 8; ++m)
#pragma unroll
    for (int n = 0; n < 4; ++n) acc[m][n] = 0;

#define STAGE_A(g_, buf_)                                                     \
  _Pragma("unroll") for (int i = 0; i < 4; ++i) {                             \
    int row_ = i * 64 + (tid >> 3);                                           \
    gload_lds16(Aop + ((size_t)(brow + row_) * KG + (g_)) * 64 + (tid & 7) * 8,\
                &sA[buf_][i * 4096 + tid * 8]);                               \
  }
#define STAGE_B(g_, buf_)                                                     \
  _Pragma("unroll") for (int i = 0; i < 4; ++i) {                             \
    int row_ = i * 64 + (tid >> 3);                                           \
    gload_lds16(Bop + ((size_t)(bcol + row_) * KG + (g_)) * 64 + (tid & 7) * 8,\
                &sB[buf_][i * 4096 + tid * 8]);                               \
  }
#define READ_A(mm, aH, aL)                                                    \
  {                                                                           \
    int fr_ = wr * 128 + (mm)*16 + l15;                                       \
    const uint16_t* rp_ = pA + fr_ * 64;                                      \
    aH = *(const bf16x8*)(rp_ + ((c16 ^ (fr_ & 7))) * 8);                     \
    aL = *(const bf16x8*)(rp_ + (((c16 + 4) ^ (fr_ & 7))) * 8);               \
  }
#define BARRIER() __builtin_amdgcn_s_barrier()
#define VM0()                                                                 \
  asm volatile("s_waitcnt vmcnt(0)" ::: "memory");                            \
  __builtin_amdgcn_sched_barrier(0)

  // prologue: stage tile 0
  STAGE_A(0, 0)
  STAGE_B(0, 0)
  VM0();
  BARRIER();

  int cur = 0;
#pragma unroll 1
  for (int g = 0; g < KG; ++g) {
    const uint16_t* pA = &sA[cur][0];
    const uint16_t* pB = &sB[cur][0];
    const bool pf = (g + 1 < KG);
    const int nxt = cur ^ 1;

    // issue A-prefetch for next tile first (HBM latency starts ticking)
    if (pf) { STAGE_A(g + 1, nxt) }

    // B frags (reused across all 4 MFMA clusters)
    bf16x8 bh[4], bl[4];
#pragma unroll
    for (int n = 0; n < 4; ++n) {
      int fc = wc * 64 + n * 16 + l15;
      const uint16_t* rp = pB + fc * 64;
      bh[n] = *(const bf16x8*)(rp + ((c16 ^ (fc & 7))) * 8);
      bl[n] = *(const bf16x8*)(rp + (((c16 + 4) ^ (fc & 7))) * 8);
    }
    // read-ahead register pipeline: reads for cluster p+1 issue before
    // cluster p's MFMAs; compiler inserts counted lgkmcnt between.
    bf16x8 a0h, a0l, a1h, a1l, a2h, a2l, a3h, a3l;
    READ_A(0, a0h, a0l)
    READ_A(1, a1h, a1l)
    READ_A(2, a2h, a2l)
    READ_A(3, a3h, a3l)
    __builtin_amdgcn_s_setprio(1);
    mfma_row(acc[0], a0h, a0l, bh, bl);
    mfma_row(acc[1], a1h, a1l, bh, bl);
    __builtin_amdgcn_s_setprio(0);
    if (pf) { STAGE_B(g + 1, nxt) }
    READ_A(4, a0h, a0l)
    READ_A(5, a1h, a1l)
    __builtin_amdgcn_s_setprio(1);
    mfma_row(acc[2], a2h, a2l, bh, bl);
    mfma_row(acc[3], a3h, a3l, bh, bl);
    __builtin_amdgcn_s_setprio(0);
    READ_A(6, a2h, a2l)
    READ_A(7, a3h, a3l)
    __builtin_amdgcn_s_setprio(1);
    mfma_row(acc[4], a0h, a0l, bh, bl);
    mfma_row(acc[5], a1h, a1l, bh, bl);
    mfma_row(acc[6], a2h, a2l, bh, bl);
    mfma_row(acc[7], a3h, a3l, bh, bl);
    __builtin_amdgcn_s_setprio(0);

    // single per-tile sync: own prefetch landed (issued ~1 tile ago -> free),
    // then barrier so (a) everyone may read buf[nxt], (b) slot overwrite of
    // buf[cur] next tile is safe.
    VM0();
    BARRIER();
    cur = nxt;
  }

  // ---- epilogue: bias + relu; store op-layout bf16 hi/lo (or fp32 last)
  float bb[4];
  int colg[4], colc[4], cole[4];
#pragma unroll
  for (int n = 0; n < 4; ++n) {
    int col = bcol + wc * 64 + n * 16 + l15;
    bb[n] = bias[col];
    colg[n] = col >> 5; colc[n] = (col >> 3) & 3; cole[n] = col & 7;
  }
#pragma unroll
  for (int m = 0; m < 8; ++m) {
#pragma unroll
    for (int j = 0; j < 4; ++j) {
      int rowY = brow + wr * 128 + m * 16 + c16 * 4 + j;  // C/D: row=(l>>4)*4+j
      int s = rowY & 7;
#pragma unroll
      for (int n = 0; n < 4; ++n) {
        float v = acc[m][n][j] + bb[n];
        v = v > 0.f ? v : 0.f;
        if (LAST) {
          Yf[(size_t)rowY * 1024 + bcol + wc * 64 + n * 16 + l15] = v;
        } else {
          uint16_t h, lo2;
          fsplit(v, h, lo2);
          size_t base = ((size_t)rowY * 32 + colg[n]) * 64;
          Yop[base + (size_t)((colc[n] ^ s)) * 8 + cole[n]] = h;
          Yop[base + (size_t)(((colc[n] + 4) ^ s)) * 8 + cole[n]] = lo2;
        }
      }
    }
  }
#undef STAGE_A
#undef STAGE_B
#undef READ_A
#undef BARRIER
#undef VM0
}

extern "C" void kernel_launch(void* const* d_in, const int* in_sizes, int n_in,
                              void* d_out, int out_size, void* d_ws, size_t ws_size,
                              hipStream_t stream) {
  (void)in_sizes; (void)n_in; (void)out_size; (void)ws_size;
  const float*   anchor = (const float*)d_in[0];
  const float*   rnd    = (const float*)d_in[1];
  const uint8_t* mask   = (const uint8_t*)d_in[2];
  const float*   enc_w0 = (const float*)d_in[3];
  const float*   enc_b0 = (const float*)d_in[4];
  const float*   enc_w  = (const float*)d_in[5];
  const float*   enc_b  = (const float*)d_in[6];
  const float*   head_w = (const float*)d_in[7];
  const float*   head_b = (const float*)d_in[8];
  float* out = (float*)d_out;

  // op-layout sizes (u16 elems): W layer = 1024*(K/32)*64 = K*2048
  const size_t WSZ0 = (size_t)512 * 2048;        // 1,048,576
  const size_t WSZ1 = (size_t)1024 * 2048;       // 2,097,152
  uint16_t* Wop = (uint16_t*)d_ws;               // 6 layers: 23 MB
  size_t WOFF[6];
  WOFF[0] = 0;
  WOFF[1] = WSZ0;
  for (int i = 2; i < 6; ++i) WOFF[i] = WOFF[i - 1] + WSZ1;
  uint16_t* Xop = Wop + WOFF[5] + WSZ1;          // 16384*1024 u16 = 32 MB
  uint16_t* Yop = Xop + (size_t)16384 * 1024;    // 16384*2048 u16 = 64 MB
  int* mflag = (int*)(Yop + (size_t)16384 * 2048);
  // Z ping-pong inside d_out (64 MB exactly); dead before final fp32 write
  uint16_t* Zop = (uint16_t*)d_out;

  // 0) mask dtype detection (graph-safe, recomputed every launch)
  detect_mask_kernel<<<1, 64, 0, stream>>>(mask, mflag);

  // 1) corruption + split + op-layout pack
  pack_kernel<<<2048, 256, 0, stream>>>(anchor, rnd, mask, mflag, Xop);

  // 2) weight prep
  wprep_kernel<<<dim3(16, 32), 256, 0, stream>>>(enc_w0, Wop + WOFF[0], 512);
  for (int i = 0; i < 3; ++i)
    wprep_kernel<<<dim3(32, 32), 256, 0, stream>>>(enc_w + (size_t)i * 1048576,
                                                   Wop + WOFF[1 + i], 1024);
  for (int i = 0; i < 2; ++i)
    wprep_kernel<<<dim3(32, 32), 256, 0, stream>>>(head_w + (size_t)i * 1048576,
                                                   Wop + WOFF[4 + i], 1024);

  // 3) 6 fused GEMM+bias+ReLU layers (256 blocks = 1/CU)
  dim3 g(256), b(512);
  gemm_kernel<512,  false><<<g, b, 0, stream>>>(Xop, Wop + WOFF[0], enc_b0,        Yop, nullptr);
  gemm_kernel<1024, false><<<g, b, 0, stream>>>(Yop, Wop + WOFF[1], enc_b,         Zop, nullptr);
  gemm_kernel<1024, false><<<g, b, 0, stream>>>(Zop, Wop + WOFF[2], enc_b + 1024,  Yop, nullptr);
  gemm_kernel<1024, false><<<g, b, 0, stream>>>(Yop, Wop + WOFF[3], enc_b + 2048,  Zop, nullptr);
  gemm_kernel<1024, false><<<g, b, 0, stream>>>(Zop, Wop + WOFF[4], head_b,        Yop, nullptr);
  gemm_kernel<1024, true ><<<g, b, 0, stream>>>(Yop, Wop + WOFF[5], head_b + 1024, nullptr, out);
}